// Round 1
// baseline (144.867 us; speedup 1.0000x reference)
//
#include <hip/hip_runtime.h>

#define TS 68          // LDS row stride (floats): 64 + 4 pad, keeps float4 alignment
#define EPSF 1e-7f

// Column softmax of w_raw: w[i][o] = exp(w_raw[i][o]-log64) / sum_i exp(...)
__global__ void softmax_w_kernel(const float* __restrict__ wraw, float* __restrict__ w) {
  int o = threadIdx.x;
  if (o >= 64) return;
  const float LOGC = 4.1588830833596715f;  // log(64)
  float s = 0.f;
  for (int i = 0; i < 64; ++i) s += expf(wraw[i * 64 + o] - LOGC);
  float inv = 1.0f / s;
  for (int i = 0; i < 64; ++i) w[i * 64 + o] = expf(wraw[i * 64 + o] - LOGC) * inv;
}

__global__ __launch_bounds__(256, 2) void mfd_fc_kernel(
    const float* __restrict__ x, const float* __restrict__ w,
    float* __restrict__ out) {
  __shared__ float Xs[64 * TS];   // X natural  [i][dd]
  __shared__ float Xt[64 * TS];   // X^T        [dd][i]
  __shared__ float At[64 * TS];   // a^T        [dd][o]
  __shared__ float Cs[64 * TS];   // c          [i][o]
  __shared__ float part[16 * TS]; // reduction partials
  __shared__ float qq[64], pp[64], sdot[64], gnorm[64];

  const int n = blockIdx.x;
  const int tid = threadIdx.x;
  const float* xn = x + (size_t)n * 4096;

  // ---- stage X into LDS (natural + transposed) ----
#pragma unroll
  for (int t = 0; t < 4; ++t) {
    int idx = tid + t * 256;        // float4 index, 1024 total
    int i = idx >> 4;               // row (16 float4 per 64-float row)
    int c4 = (idx & 15) << 2;       // col
    float4 v = reinterpret_cast<const float4*>(xn)[idx];
    *reinterpret_cast<float4*>(&Xs[i * TS + c4]) = v;
    Xt[(c4 + 0) * TS + i] = v.x;
    Xt[(c4 + 1) * TS + i] = v.y;
    Xt[(c4 + 2) * TS + i] = v.z;
    Xt[(c4 + 3) * TS + i] = v.w;
  }
  __syncthreads();

  // qq[i] = ||x_i||^2 ; init a_o = x_0 (At[dd][o] = X[0][dd])
  if (tid < 64) {
    float s = 0.f;
    for (int dd = 0; dd < 64; ++dd) { float v = Xt[dd * TS + tid]; s = fmaf(v, v, s); }
    qq[tid] = s;
  }
  for (int idx = tid; idx < 4096; idx += 256) {
    int dd = idx >> 6, o = idx & 63;
    At[dd * TS + o] = Xs[dd];
  }
  __syncthreads();

  const int ig = tid >> 4, og = tid & 15;
  const int i0 = ig << 2, o0 = og << 2;

  for (int it = 0; it < 3; ++it) {
    // pp[o] = ||a_o||^2
    if (tid < 64) {
      float s = 0.f;
      for (int dd = 0; dd < 64; ++dd) { float v = At[dd * TS + tid]; s = fmaf(v, v, s); }
      pp[tid] = s;
    }
    __syncthreads();

    // ---- GEMM 1: dot[i][o] = sum_k X[i][k] * a[o][k], 4x4 tile per thread ----
    float acc[4][4] = {};
    for (int k = 0; k < 64; ++k) {
      float4 xv = *reinterpret_cast<const float4*>(&Xt[k * TS + i0]);
      float4 av = *reinterpret_cast<const float4*>(&At[k * TS + o0]);
      float xa[4] = {xv.x, xv.y, xv.z, xv.w};
      float aa[4] = {av.x, av.y, av.z, av.w};
#pragma unroll
      for (int ii = 0; ii < 4; ++ii)
#pragma unroll
        for (int oo = 0; oo < 4; ++oo)
          acc[ii][oo] = fmaf(xa[ii], aa[oo], acc[ii][oo]);
    }

    // ---- elementwise: c = w * theta/||v||, ||v||^2 via scalar identity ----
    float4 ppv4 = *reinterpret_cast<const float4*>(&pp[o0]);
    float ppv[4] = {ppv4.x, ppv4.y, ppv4.z, ppv4.w};
    float sd[4] = {0.f, 0.f, 0.f, 0.f};
#pragma unroll
    for (int ii = 0; ii < 4; ++ii) {
      float qv = qq[i0 + ii];
      float4 w4 = *reinterpret_cast<const float4*>(&w[(i0 + ii) * 64 + o0]);
      float wa[4] = {w4.x, w4.y, w4.z, w4.w};
      float cr[4];
#pragma unroll
      for (int oo = 0; oo < 4; ++oo) {
        float raw = acc[ii][oo];
        float dot = fminf(fmaxf(raw, -1.0f + EPSF), 1.0f - EPSF);
        float theta = acosf(dot);
        float nv2 = qv - 2.0f * dot * raw + dot * dot * ppv[oo];
        float nv = sqrtf(fmaxf(nv2, 0.f));
        float factor = (nv < EPSF) ? 1.0f : theta / nv;
        float c = wa[oo] * factor;
        cr[oo] = c;
        sd[oo] = fmaf(c, dot, sd[oo]);
      }
      *reinterpret_cast<float4*>(&Cs[(i0 + ii) * TS + o0]) =
          make_float4(cr[0], cr[1], cr[2], cr[3]);
    }
    *reinterpret_cast<float4*>(&part[ig * TS + o0]) =
        make_float4(sd[0], sd[1], sd[2], sd[3]);
    __syncthreads();

    // sdot[o] = sum_i c[i][o]*dot[i][o]
    if (tid < 64) {
      float s = 0.f;
      for (int r = 0; r < 16; ++r) s += part[r * TS + tid];
      sdot[tid] = s;
    }
    __syncthreads();

    // ---- GEMM 2: G[o'][dd] = sum_i c[i][o'] * X[i][dd]  (o' = i0.., dd = o0..) ----
    float g[4][4] = {};
    for (int i = 0; i < 64; ++i) {
      float4 cv = *reinterpret_cast<const float4*>(&Cs[i * TS + i0]);
      float4 xv = *reinterpret_cast<const float4*>(&Xs[i * TS + o0]);
      float ca[4] = {cv.x, cv.y, cv.z, cv.w};
      float xa[4] = {xv.x, xv.y, xv.z, xv.w};
#pragma unroll
      for (int oo = 0; oo < 4; ++oo)
#pragma unroll
        for (int jj = 0; jj < 4; ++jj)
          g[oo][jj] = fmaf(ca[oo], xa[jj], g[oo][jj]);
    }

    // grad = G - sdot[o']*a[o'] ; accumulate ||grad||^2 partials
    float4 sdv4 = *reinterpret_cast<const float4*>(&sdot[i0]);
    float sdv[4] = {sdv4.x, sdv4.y, sdv4.z, sdv4.w};
    float av[4][4];
    float gn2[4] = {0.f, 0.f, 0.f, 0.f};
#pragma unroll
    for (int oo = 0; oo < 4; ++oo) {
#pragma unroll
      for (int jj = 0; jj < 4; ++jj) {
        float a_ = At[(o0 + jj) * TS + (i0 + oo)];
        float gv = g[oo][jj] - sdv[oo] * a_;
        av[oo][jj] = a_;
        g[oo][jj] = gv;
        gn2[oo] = fmaf(gv, gv, gn2[oo]);
      }
    }
    *reinterpret_cast<float4*>(&part[og * TS + i0]) =
        make_float4(gn2[0], gn2[1], gn2[2], gn2[3]);
    __syncthreads();

    if (tid < 64) {
      float s = 0.f;
      for (int r = 0; r < 16; ++r) s += part[r * TS + tid];
      gnorm[tid] = sqrtf(s);
    }
    __syncthreads();

    // ---- exp map: a' = cos(n)*a + sinc(n)*grad ----
    float4 gnv4 = *reinterpret_cast<const float4*>(&gnorm[i0]);
    float gnv[4] = {gnv4.x, gnv4.y, gnv4.z, gnv4.w};
    if (it < 2) {
#pragma unroll
      for (int oo = 0; oo < 4; ++oo) {
        float nrm = gnv[oo];
        float cn = cosf(nrm);
        float sn = (nrm < EPSF) ? 1.0f : sinf(nrm) / nrm;
#pragma unroll
        for (int jj = 0; jj < 4; ++jj) {
          float anew = cn * av[oo][jj] + sn * g[oo][jj];
          At[(o0 + jj) * TS + (i0 + oo)] = anew;
        }
      }
      __syncthreads();
    } else {
      float* outn = out + (size_t)n * 4096;
#pragma unroll
      for (int oo = 0; oo < 4; ++oo) {
        float nrm = gnv[oo];
        float cn = cosf(nrm);
        float sn = (nrm < EPSF) ? 1.0f : sinf(nrm) / nrm;
        float r[4];
#pragma unroll
        for (int jj = 0; jj < 4; ++jj) r[jj] = cn * av[oo][jj] + sn * g[oo][jj];
        *reinterpret_cast<float4*>(&outn[(i0 + oo) * 64 + o0]) =
            make_float4(r[0], r[1], r[2], r[3]);
      }
    }
  }
}

extern "C" void kernel_launch(void* const* d_in, const int* in_sizes, int n_in,
                              void* d_out, int out_size, void* d_ws, size_t ws_size,
                              hipStream_t stream) {
  const float* x = (const float*)d_in[0];      // (B,L,C_in,d) fp32
  const float* wraw = (const float*)d_in[1];   // (C_in,C_out) fp32
  float* out = (float*)d_out;                  // (B,L,C_out,d) fp32
  float* w = (float*)d_ws;                     // normalized weights (64*64 fp32)

  int N = in_sizes[0] / 4096;                  // B*L = 1024

  softmax_w_kernel<<<1, 64, 0, stream>>>(wraw, w);
  mfd_fc_kernel<<<N, 256, 0, stream>>>(x, w, out);
}

// Round 2
// 118.905 us; speedup vs baseline: 1.2183x; 1.2183x over previous
//
#include <hip/hip_runtime.h>

#define EPSF 1e-7f
#define TS2 72  // bf16 row stride: 64 + 8 pad -> 144B rows, 16B-aligned, bank-rotating

typedef __bf16 bf16;
typedef __attribute__((ext_vector_type(8))) __bf16 bf16x8;
typedef __attribute__((ext_vector_type(4))) __bf16 bf16x4;
typedef __attribute__((ext_vector_type(4))) float f32x4;

// Column softmax of w_raw: w[i][o] = exp(w_raw[i][o]-log64) / sum_i exp(...)
__global__ void softmax_w_kernel(const float* __restrict__ wraw, float* __restrict__ w) {
  int o = threadIdx.x;
  if (o >= 64) return;
  const float LOGC = 4.1588830833596715f;  // log(64)
  float s = 0.f;
  for (int i = 0; i < 64; ++i) s += expf(wraw[i * 64 + o] - LOGC);
  float inv = 1.0f / s;
  for (int i = 0; i < 64; ++i) w[i * 64 + o] = expf(wraw[i * 64 + o] - LOGC) * inv;
}

// One block = one sample n. 4 waves; wave w owns o-rows [16w, 16w+16).
// GEMM1 (MFMA): dotT[o][i] = sum_dd a[o][dd] * x[i][dd]   (A=Arow, B=Xrow)
// GEMM2 (MFMA): G[o][dd]   = sum_i  c[i][o] * x[i][dd]    (A=Ct,   B=Xt)
// C/D lane layout (m89/m91): row(M) = quad*4+reg, col(N) = lane&15 (+16*tile).
// All per-o reductions (pp, sdot, ||grad||) are xor-shuffles in the 16-lane
// group; Ct/Arow rows are same-wave-private -> NO barriers in the main loop.
__global__ __launch_bounds__(256, 4) void mfd_fc_mfma(
    const float* __restrict__ x, const float* __restrict__ w,
    float* __restrict__ out) {
  __shared__ bf16 Xrow[64 * TS2];  // [i][dd]
  __shared__ bf16 Xt[64 * TS2];    // [dd][i]
  __shared__ bf16 Arow[64 * TS2];  // [o][dd]
  __shared__ bf16 Ct[64 * TS2];    // [o][i]

  const int n = blockIdx.x;
  const int tid = threadIdx.x;
  const int wv = tid >> 6;
  const int lane = tid & 63;
  const int ln15 = lane & 15;
  const int quad = lane >> 4;
  const int obase = 16 * wv + 4 * quad;  // this lane's 4 o-rows: obase..obase+3
  const float* xn = x + (size_t)n * 4096;

  // ---- stage X -> LDS as bf16, natural + transposed ----
#pragma unroll
  for (int t = 0; t < 4; ++t) {
    int idx = tid + t * 256;   // float4 index
    int i = idx >> 4;
    int c4 = (idx & 15) << 2;
    float4 v = reinterpret_cast<const float4*>(xn)[idx];
    bf16x4 b;
    b[0] = (bf16)v.x; b[1] = (bf16)v.y; b[2] = (bf16)v.z; b[3] = (bf16)v.w;
    *reinterpret_cast<bf16x4*>(&Xrow[i * TS2 + c4]) = b;
    Xt[(c4 + 0) * TS2 + i] = b[0];
    Xt[(c4 + 1) * TS2 + i] = b[1];
    Xt[(c4 + 2) * TS2 + i] = b[2];
    Xt[(c4 + 3) * TS2 + i] = b[3];
  }

  // ---- preload w fragment (fixed lane->(i,o) map, reused all 3 iters) ----
  float wf[4][4];
#pragma unroll
  for (int t = 0; t < 4; ++t)
#pragma unroll
    for (int r = 0; r < 4; ++r)
      wf[t][r] = w[(16 * t + ln15) * 64 + obase + r];

  // ---- a := x0 (fp32 register state; dd = 16t + ln15, same for all r) ----
  float a_reg[4][4];
#pragma unroll
  for (int t = 0; t < 4; ++t) {
    float v = xn[16 * t + ln15];
#pragma unroll
    for (int r = 0; r < 4; ++r) a_reg[t][r] = v;
  }
  // initial Arow (own rows only)
#pragma unroll
  for (int t = 0; t < 4; ++t)
#pragma unroll
    for (int r = 0; r < 4; ++r)
      Arow[(obase + r) * TS2 + 16 * t + ln15] = (bf16)a_reg[t][r];

  __syncthreads();  // X staging visible to all waves (the ONLY barrier)

  const bf16* arowbase = &Arow[(16 * wv + ln15) * TS2];
  const bf16* ctbase = &Ct[(16 * wv + ln15) * TS2];

  for (int it = 0; it < 3; ++it) {
    // pp[r] = ||a_o||^2 via xor-shuffle over the 16-lane (dd) group
    float pp[4];
#pragma unroll
    for (int r = 0; r < 4; ++r) {
      float s = 0.f;
#pragma unroll
      for (int t = 0; t < 4; ++t) s = fmaf(a_reg[t][r], a_reg[t][r], s);
      s += __shfl_xor(s, 1); s += __shfl_xor(s, 2);
      s += __shfl_xor(s, 4); s += __shfl_xor(s, 8);
      pp[r] = s;
    }

    // ---- GEMM1: dotT[o][i], K = dd = 64 (2 MFMA k-steps) ----
    f32x4 acc[4] = {f32x4{0,0,0,0}, f32x4{0,0,0,0}, f32x4{0,0,0,0}, f32x4{0,0,0,0}};
#pragma unroll
    for (int ks = 0; ks < 2; ++ks) {
      bf16x8 af = *reinterpret_cast<const bf16x8*>(&arowbase[ks * 32 + quad * 8]);
#pragma unroll
      for (int t = 0; t < 4; ++t) {
        bf16x8 bfr = *reinterpret_cast<const bf16x8*>(
            &Xrow[(16 * t + ln15) * TS2 + ks * 32 + quad * 8]);
        acc[t] = __builtin_amdgcn_mfma_f32_16x16x32_bf16(af, bfr, acc[t], 0, 0, 0);
      }
    }

    // ---- elementwise: c = w * theta/||v||; ||v||^2 = 1 - 2*dot*raw + dot^2*pp
    float sd[4] = {0.f, 0.f, 0.f, 0.f};
#pragma unroll
    for (int t = 0; t < 4; ++t) {
#pragma unroll
      for (int r = 0; r < 4; ++r) {
        float raw = acc[t][r];
        float dot = fminf(fmaxf(raw, -1.0f + EPSF), 1.0f - EPSF);
        float theta = acosf(dot);
        float nv2 = fmaf(dot * dot, pp[r], fmaf(-2.0f * dot, raw, 1.0f));
        float nv = sqrtf(fmaxf(nv2, 0.f));
        float factor = (nv < EPSF) ? 1.0f : theta / nv;
        bf16 cb = (bf16)(wf[t][r] * factor);
        Ct[(obase + r) * TS2 + 16 * t + ln15] = cb;     // same-wave rows
        sd[r] = fmaf((float)cb, dot, sd[r]);            // bf16-consistent sdot
      }
    }
#pragma unroll
    for (int r = 0; r < 4; ++r) {
      float s = sd[r];
      s += __shfl_xor(s, 1); s += __shfl_xor(s, 2);
      s += __shfl_xor(s, 4); s += __shfl_xor(s, 8);
      sd[r] = s;  // sdot[o], o = obase + r
    }

    // ---- GEMM2: G[o][dd], K = i = 64 ----
    f32x4 g[4] = {f32x4{0,0,0,0}, f32x4{0,0,0,0}, f32x4{0,0,0,0}, f32x4{0,0,0,0}};
#pragma unroll
    for (int ks = 0; ks < 2; ++ks) {
      bf16x8 af = *reinterpret_cast<const bf16x8*>(&ctbase[ks * 32 + quad * 8]);
#pragma unroll
      for (int t = 0; t < 4; ++t) {
        bf16x8 bfr = *reinterpret_cast<const bf16x8*>(
            &Xt[(16 * t + ln15) * TS2 + ks * 32 + quad * 8]);
        g[t] = __builtin_amdgcn_mfma_f32_16x16x32_bf16(af, bfr, g[t], 0, 0, 0);
      }
    }

    // ---- grad = G - sdot*a ; gnorm via shuffle; exp map (all in registers) --
    float gn2[4] = {0.f, 0.f, 0.f, 0.f};
#pragma unroll
    for (int t = 0; t < 4; ++t)
#pragma unroll
      for (int r = 0; r < 4; ++r) {
        float v = g[t][r] - sd[r] * a_reg[t][r];
        g[t][r] = v;
        gn2[r] = fmaf(v, v, gn2[r]);
      }
#pragma unroll
    for (int r = 0; r < 4; ++r) {
      float s = gn2[r];
      s += __shfl_xor(s, 1); s += __shfl_xor(s, 2);
      s += __shfl_xor(s, 4); s += __shfl_xor(s, 8);
      float nrm = sqrtf(s);
      float cn = cosf(nrm);
      float sn = (nrm < EPSF) ? 1.0f : sinf(nrm) / nrm;
#pragma unroll
      for (int t = 0; t < 4; ++t)
        a_reg[t][r] = fmaf(cn, a_reg[t][r], sn * g[t][r]);
    }
    if (it < 2) {
#pragma unroll
      for (int t = 0; t < 4; ++t)
#pragma unroll
        for (int r = 0; r < 4; ++r)
          Arow[(obase + r) * TS2 + 16 * t + ln15] = (bf16)a_reg[t][r];
    }
  }

  // ---- store fp32 output: out[n][o][dd] ----
  float* outn = out + (size_t)n * 4096;
#pragma unroll
  for (int r = 0; r < 4; ++r)
#pragma unroll
    for (int t = 0; t < 4; ++t)
      outn[(obase + r) * 64 + 16 * t + ln15] = a_reg[t][r];
}

extern "C" void kernel_launch(void* const* d_in, const int* in_sizes, int n_in,
                              void* d_out, int out_size, void* d_ws, size_t ws_size,
                              hipStream_t stream) {
  const float* x = (const float*)d_in[0];    // (B,L,64,64) fp32, unit rows
  const float* wraw = (const float*)d_in[1]; // (64,64) fp32
  float* out = (float*)d_out;                // (B,L,64,64) fp32
  float* w = (float*)d_ws;                   // normalized weights 64x64 fp32

  int N = in_sizes[0] / 4096;  // B*L = 1024

  softmax_w_kernel<<<1, 64, 0, stream>>>(wraw, w);
  mfd_fc_mfma<<<N, 256, 0, stream>>>(x, w, out);
}

// Round 3
// 101.526 us; speedup vs baseline: 1.4269x; 1.1712x over previous
//
#include <hip/hip_runtime.h>

#define EPSF 1e-7f
#define TS2 72   // bf16 row stride: 64 + 8 pad
#define OFS 68   // fp32 out-staging row stride

typedef __bf16 bf16;
typedef __attribute__((ext_vector_type(8))) __bf16 bf16x8;
typedef __attribute__((ext_vector_type(4))) __bf16 bf16x4;
typedef __attribute__((ext_vector_type(4))) float f32x4;

// Parallel column softmax: 1 block x 1024 threads, coalesced, LDS reduce.
__global__ __launch_bounds__(1024) void softmax_w_kernel(
    const float* __restrict__ wraw, float* __restrict__ w) {
  __shared__ float part[16][64];
  __shared__ float inv[64];
  const float LOGC = 4.1588830833596715f;  // log(64)
  int tid = threadIdx.x;
  int o = tid & 63, seg = tid >> 6;  // seg owns rows 4*seg..4*seg+3
  float e[4];
  float s = 0.f;
#pragma unroll
  for (int j = 0; j < 4; ++j) {
    int i = seg * 4 + j;
    e[j] = expf(wraw[i * 64 + o] - LOGC);
    s += e[j];
  }
  part[seg][o] = s;
  __syncthreads();
  if (tid < 64) {
    float t = 0.f;
#pragma unroll
    for (int r = 0; r < 16; ++r) t += part[r][tid];
    inv[tid] = 1.0f / t;
  }
  __syncthreads();
  float iv = inv[o];
#pragma unroll
  for (int j = 0; j < 4; ++j) {
    int i = seg * 4 + j;
    w[i * 64 + o] = e[j] * iv;
  }
}

// acos via A&S 4.4.45: |err| <= ~7e-5 rad, sqrt + 4 FMA + select.
__device__ __forceinline__ float fast_acos(float x) {
  float ax = fabsf(x);
  float r = sqrtf(fmaxf(1.0f - ax, 0.0f));
  float p = fmaf(fmaf(fmaf(-0.0187292994f, ax, 0.0742610070f), ax,
                      -0.2121144013f), ax, 1.5707288f);
  float t = r * p;
  return (x < 0.0f) ? (3.14159265358979f - t) : t;
}

// One block = one sample n. 4 waves; wave w owns o-rows [16w,16w+16).
// GEMM1 (MFMA): dotT[o][i] = sum_dd a[o][dd]*x[i][dd]  (A=Arow, B=Xrow)
// GEMM2 (MFMA): G[o][dd]   = sum_i  c[i][o]*x[i][dd]   (A=Ct,   B=Xt)
// All per-o reductions are 16-lane xor-shuffles; Ct/Arow rows are
// wave-private -> no barriers in the main loop.
__global__ __launch_bounds__(256, 4) void mfd_fc_mfma(
    const float* __restrict__ x, const float* __restrict__ w,
    float* __restrict__ out) {
  __shared__ __align__(16) char smem[4 * 64 * TS2 * sizeof(bf16)];
  bf16* Xrow = (bf16*)smem;            // [i][dd]
  bf16* Xt   = Xrow + 64 * TS2;        // [dd][i]
  bf16* Arow = Xt + 64 * TS2;          // [o][dd]
  bf16* Ct   = Arow + 64 * TS2;        // [o][i]
  float* OutF = (float*)smem;          // epilogue staging, aliases Xrow+Xt
                                       // (64*OFS*4 = 17408 <= 18432)

  const int n = blockIdx.x;
  const int tid = threadIdx.x;
  const int wv = tid >> 6;
  const int lane = tid & 63;
  const int ln15 = lane & 15;
  const int quad = lane >> 4;
  const int obase = 16 * wv + 4 * quad;
  const float* xn = x + (size_t)n * 4096;

  // ---- stage X -> LDS as bf16, natural + transposed ----
#pragma unroll
  for (int t = 0; t < 4; ++t) {
    int idx = tid + t * 256;  // float4 index
    int i = idx >> 4;
    int c4 = (idx & 15) << 2;
    float4 v = reinterpret_cast<const float4*>(xn)[idx];
    bf16x4 b;
    b[0] = (bf16)v.x; b[1] = (bf16)v.y; b[2] = (bf16)v.z; b[3] = (bf16)v.w;
    *reinterpret_cast<bf16x4*>(&Xrow[i * TS2 + c4]) = b;
    Xt[(c4 + 0) * TS2 + i] = b[0];
    Xt[(c4 + 1) * TS2 + i] = b[1];
    Xt[(c4 + 2) * TS2 + i] = b[2];
    Xt[(c4 + 3) * TS2 + i] = b[3];
  }

  // ---- preload w fragment (lane->(i,o) map fixed across iters) ----
  float wf[4][4];
#pragma unroll
  for (int t = 0; t < 4; ++t)
#pragma unroll
    for (int r = 0; r < 4; ++r)
      wf[t][r] = w[(16 * t + ln15) * 64 + obase + r];

  // ---- a := x0 ----
  float a_reg[4][4];
#pragma unroll
  for (int t = 0; t < 4; ++t) {
    float v = xn[16 * t + ln15];
#pragma unroll
    for (int r = 0; r < 4; ++r) a_reg[t][r] = v;
  }
#pragma unroll
  for (int t = 0; t < 4; ++t)
#pragma unroll
    for (int r = 0; r < 4; ++r)
      Arow[(obase + r) * TS2 + 16 * t + ln15] = (bf16)a_reg[t][r];

  __syncthreads();  // X staging + Arow init visible

  const bf16* arowbase = &Arow[(16 * wv + ln15) * TS2];
  const bf16* ctbase = &Ct[(16 * wv + ln15) * TS2];

  for (int it = 0; it < 3; ++it) {
    // pp[r] = ||a_o||^2 via 16-lane xor-shuffle
    float pp[4];
#pragma unroll
    for (int r = 0; r < 4; ++r) {
      float s = 0.f;
#pragma unroll
      for (int t = 0; t < 4; ++t) s = fmaf(a_reg[t][r], a_reg[t][r], s);
      s += __shfl_xor(s, 1); s += __shfl_xor(s, 2);
      s += __shfl_xor(s, 4); s += __shfl_xor(s, 8);
      pp[r] = s;
    }

    // ---- GEMM1: dotT[o][i] ----
    f32x4 acc[4] = {f32x4{0,0,0,0}, f32x4{0,0,0,0}, f32x4{0,0,0,0}, f32x4{0,0,0,0}};
#pragma unroll
    for (int ks = 0; ks < 2; ++ks) {
      bf16x8 af = *reinterpret_cast<const bf16x8*>(&arowbase[ks * 32 + quad * 8]);
#pragma unroll
      for (int t = 0; t < 4; ++t) {
        bf16x8 bfr = *reinterpret_cast<const bf16x8*>(
            &Xrow[(16 * t + ln15) * TS2 + ks * 32 + quad * 8]);
        acc[t] = __builtin_amdgcn_mfma_f32_16x16x32_bf16(af, bfr, acc[t], 0, 0, 0);
      }
    }

    // ---- elementwise: c = w * theta * rsqrt(||v||^2) ----
    float sd[4] = {0.f, 0.f, 0.f, 0.f};
#pragma unroll
    for (int t = 0; t < 4; ++t) {
#pragma unroll
      for (int r = 0; r < 4; ++r) {
        float raw = acc[t][r];
        float dot = fminf(fmaxf(raw, -1.0f + EPSF), 1.0f - EPSF);
        float theta = fast_acos(dot);
        float nv2 = fmaf(dot * dot, pp[r], fmaf(-2.0f * dot, raw, 1.0f));
        float factor = (nv2 < 1e-14f) ? 1.0f : theta * rsqrtf(nv2);
        bf16 cb = (bf16)(wf[t][r] * factor);
        Ct[(obase + r) * TS2 + 16 * t + ln15] = cb;
        sd[r] = fmaf((float)cb, dot, sd[r]);
      }
    }
#pragma unroll
    for (int r = 0; r < 4; ++r) {
      float s = sd[r];
      s += __shfl_xor(s, 1); s += __shfl_xor(s, 2);
      s += __shfl_xor(s, 4); s += __shfl_xor(s, 8);
      sd[r] = s;
    }

    // ---- GEMM2: G[o][dd] ----
    f32x4 g[4] = {f32x4{0,0,0,0}, f32x4{0,0,0,0}, f32x4{0,0,0,0}, f32x4{0,0,0,0}};
#pragma unroll
    for (int ks = 0; ks < 2; ++ks) {
      bf16x8 af = *reinterpret_cast<const bf16x8*>(&ctbase[ks * 32 + quad * 8]);
#pragma unroll
      for (int t = 0; t < 4; ++t) {
        bf16x8 bfr = *reinterpret_cast<const bf16x8*>(
            &Xt[(16 * t + ln15) * TS2 + ks * 32 + quad * 8]);
        g[t] = __builtin_amdgcn_mfma_f32_16x16x32_bf16(af, bfr, g[t], 0, 0, 0);
      }
    }

    // ---- grad = G - sdot*a ; exp map ----
    float gn2[4] = {0.f, 0.f, 0.f, 0.f};
#pragma unroll
    for (int t = 0; t < 4; ++t)
#pragma unroll
      for (int r = 0; r < 4; ++r) {
        float v = g[t][r] - sd[r] * a_reg[t][r];
        g[t][r] = v;
        gn2[r] = fmaf(v, v, gn2[r]);
      }
#pragma unroll
    for (int r = 0; r < 4; ++r) {
      float s = gn2[r];
      s += __shfl_xor(s, 1); s += __shfl_xor(s, 2);
      s += __shfl_xor(s, 4); s += __shfl_xor(s, 8);
      float nrm = sqrtf(s);
      float sn_, cn;
      __sincosf(nrm, &sn_, &cn);
      float sn = (nrm < EPSF) ? 1.0f : sn_ / nrm;
#pragma unroll
      for (int t = 0; t < 4; ++t)
        a_reg[t][r] = fmaf(cn, a_reg[t][r], sn * g[t][r]);
    }
    if (it < 2) {
#pragma unroll
      for (int t = 0; t < 4; ++t)
#pragma unroll
        for (int r = 0; r < 4; ++r)
          Arow[(obase + r) * TS2 + 16 * t + ln15] = (bf16)a_reg[t][r];
    }
  }

  // ---- epilogue: LDS fp32 transpose -> coalesced float4 stores ----
  __syncthreads();  // all waves done with Xrow/Xt before aliasing
#pragma unroll
  for (int t = 0; t < 4; ++t)
#pragma unroll
    for (int r = 0; r < 4; ++r)
      OutF[(obase + r) * OFS + 16 * t + ln15] = a_reg[t][r];
  __syncthreads();
  float* outn = out + (size_t)n * 4096;
#pragma unroll
  for (int t = 0; t < 4; ++t) {
    int idx = tid + t * 256;
    int row = idx >> 4, col4 = (idx & 15) << 2;
    float4 v = *reinterpret_cast<const float4*>(&OutF[row * OFS + col4]);
    reinterpret_cast<float4*>(outn)[idx] = v;
  }
}

extern "C" void kernel_launch(void* const* d_in, const int* in_sizes, int n_in,
                              void* d_out, int out_size, void* d_ws, size_t ws_size,
                              hipStream_t stream) {
  const float* x = (const float*)d_in[0];    // (B,L,64,64) fp32, unit rows
  const float* wraw = (const float*)d_in[1]; // (64,64) fp32
  float* out = (float*)d_out;                // (B,L,64,64) fp32
  float* w = (float*)d_ws;                   // normalized weights 64x64 fp32

  int N = in_sizes[0] / 4096;  // B*L = 1024

  softmax_w_kernel<<<1, 1024, 0, stream>>>(wraw, w);
  mfd_fc_mfma<<<N, 256, 0, stream>>>(x, w, out);
}

// Round 4
// 97.516 us; speedup vs baseline: 1.4856x; 1.0411x over previous
//
#include <hip/hip_runtime.h>

#define EPSF 1e-7f
#define TS2 72   // bf16 row stride: 64 + 8 pad (16B-aligned rows, bank-rotating)
#define OFS 68   // fp32 out-staging row stride

typedef __bf16 bf16;
typedef __attribute__((ext_vector_type(8))) __bf16 bf16x8;
typedef __attribute__((ext_vector_type(4))) __bf16 bf16x4;
typedef __attribute__((ext_vector_type(4))) float f32x4;

// Sum over each 16-lane group via DPP involutions: xor1, xor2 (quad_perm),
// xor7 (ROW_HALF_MIRROR), xor15 (ROW_MIRROR). 8 VALU, zero LDS traffic.
__device__ __forceinline__ float dpp_sum16(float v) {
  int x;
  x = __builtin_amdgcn_update_dpp(0, __builtin_bit_cast(int, v), 0xB1, 0xf, 0xf, true);
  v += __builtin_bit_cast(float, x);                     // + lane^1
  x = __builtin_amdgcn_update_dpp(0, __builtin_bit_cast(int, v), 0x4E, 0xf, 0xf, true);
  v += __builtin_bit_cast(float, x);                     // + lane^2
  x = __builtin_amdgcn_update_dpp(0, __builtin_bit_cast(int, v), 0x141, 0xf, 0xf, true);
  v += __builtin_bit_cast(float, x);                     // + lane^7 (half mirror)
  x = __builtin_amdgcn_update_dpp(0, __builtin_bit_cast(int, v), 0x140, 0xf, 0xf, true);
  v += __builtin_bit_cast(float, x);                     // + lane^15 (mirror)
  return v;
}

// acos via A&S 4.4.45: |err| <= ~7e-5 rad.
__device__ __forceinline__ float fast_acos(float x) {
  float ax = fabsf(x);
  float r = sqrtf(fmaxf(1.0f - ax, 0.0f));
  float p = fmaf(fmaf(fmaf(-0.0187292994f, ax, 0.0742610070f), ax,
                      -0.2121144013f), ax, 1.5707288f);
  float t = r * p;
  return (x < 0.0f) ? (3.14159265358979f - t) : t;
}

// One block = one sample n. 4 waves; wave wv owns o-rows [16wv,16wv+16).
// GEMM1 (MFMA): dotT[o][i] = sum_dd a[o][dd]*x[i][dd]  (A=Arow, B=Xrow)
// GEMM2 (MFMA): G[o][dd]   = sum_i  c[i][o]*x[i][dd]   (A=Ct,   B=Xt)
// All per-o reductions are DPP sums in the 16-lane group; Ct/Arow rows are
// wave-private -> no barriers in the main loop. Softmax(w) is recomputed
// per-wave (each wave only needs its own 16 columns; -log64 cancels).
__global__ __launch_bounds__(256, 4) void mfd_fc_mfma(
    const float* __restrict__ x, const float* __restrict__ wraw,
    float* __restrict__ out) {
  __shared__ __align__(16) char smem[4 * 64 * TS2 * sizeof(bf16)];
  bf16* Xrow = (bf16*)smem;            // [i][dd]
  bf16* Xt   = Xrow + 64 * TS2;        // [dd][i]
  bf16* Arow = Xt + 64 * TS2;          // [o][dd]
  bf16* Ct   = Arow + 64 * TS2;        // [o][i]
  float* OutF = (float*)smem;          // epilogue staging, aliases Xrow+Xt

  const int n = blockIdx.x;
  const int tid = threadIdx.x;
  const int wv = tid >> 6;
  const int lane = tid & 63;
  const int ln15 = lane & 15;
  const int quad = lane >> 4;
  const int obase = 16 * wv + 4 * quad;
  const float* xn = x + (size_t)n * 4096;

  // ---- phase 1: stage X -> Xrow (bf16), coalesced float4 loads ----
#pragma unroll
  for (int t = 0; t < 4; ++t) {
    int idx = tid + t * 256;  // float4 index
    int i = idx >> 4;
    int c4 = (idx & 15) << 2;
    float4 v = reinterpret_cast<const float4*>(xn)[idx];
    bf16x4 b;
    b[0] = (bf16)v.x; b[1] = (bf16)v.y; b[2] = (bf16)v.z; b[3] = (bf16)v.w;
    *reinterpret_cast<bf16x4*>(&Xrow[i * TS2 + c4]) = b;
  }

  // ---- per-wave softmax of wraw columns [obase..obase+3] ----
  float wf[4][4];  // e -> normalized w, in place
  {
    float cs[4] = {0.f, 0.f, 0.f, 0.f};
#pragma unroll
    for (int t = 0; t < 4; ++t) {
      float4 wr = *reinterpret_cast<const float4*>(&wraw[(16 * t + ln15) * 64 + obase]);
      wf[t][0] = __expf(wr.x); wf[t][1] = __expf(wr.y);
      wf[t][2] = __expf(wr.z); wf[t][3] = __expf(wr.w);
#pragma unroll
      for (int r = 0; r < 4; ++r) cs[r] += wf[t][r];
    }
#pragma unroll
    for (int r = 0; r < 4; ++r) {
      float inv = 1.0f / dpp_sum16(cs[r]);  // column sum over all 64 i
#pragma unroll
      for (int t = 0; t < 4; ++t) wf[t][r] *= inv;
    }
  }

  // ---- a := x0 (fp32; dd = 16t+ln15, same value for all r) ----
  float a_reg[4][4];
#pragma unroll
  for (int t = 0; t < 4; ++t) {
    float v = xn[16 * t + ln15];
#pragma unroll
    for (int r = 0; r < 4; ++r) a_reg[t][r] = v;
  }
#pragma unroll
  for (int t = 0; t < 4; ++t)
#pragma unroll
    for (int r = 0; r < 4; ++r)
      Arow[(obase + r) * TS2 + 16 * t + ln15] = (bf16)a_reg[t][r];

  __syncthreads();  // Xrow complete

  // ---- phase 2: build Xt from Xrow (u16 column reads are pair-broadcast) --
  {
    int dd = tid & 63, ih = tid >> 6;  // i-range [16*ih, 16*ih+16)
    bf16 tmp[16];
#pragma unroll
    for (int j = 0; j < 16; ++j) tmp[j] = Xrow[(16 * ih + j) * TS2 + dd];
    *reinterpret_cast<bf16x8*>(&Xt[dd * TS2 + 16 * ih]) =
        *reinterpret_cast<bf16x8*>(&tmp[0]);
    *reinterpret_cast<bf16x8*>(&Xt[dd * TS2 + 16 * ih + 8]) =
        *reinterpret_cast<bf16x8*>(&tmp[8]);
  }
  __syncthreads();  // Xt complete; Xrow/Xt read-only from here

  const bf16* arowbase = &Arow[(16 * wv + ln15) * TS2];
  const bf16* ctbase = &Ct[(16 * wv + ln15) * TS2];

  for (int it = 0; it < 3; ++it) {
    // pp[r] = ||a_o||^2
    float pp[4];
#pragma unroll
    for (int r = 0; r < 4; ++r) {
      float s = 0.f;
#pragma unroll
      for (int t = 0; t < 4; ++t) s = fmaf(a_reg[t][r], a_reg[t][r], s);
      pp[r] = dpp_sum16(s);
    }

    // ---- GEMM1: dotT[o][i] ----
    f32x4 acc[4] = {f32x4{0,0,0,0}, f32x4{0,0,0,0}, f32x4{0,0,0,0}, f32x4{0,0,0,0}};
#pragma unroll
    for (int ks = 0; ks < 2; ++ks) {
      bf16x8 af = *reinterpret_cast<const bf16x8*>(&arowbase[ks * 32 + quad * 8]);
#pragma unroll
      for (int t = 0; t < 4; ++t) {
        bf16x8 bfr = *reinterpret_cast<const bf16x8*>(
            &Xrow[(16 * t + ln15) * TS2 + ks * 32 + quad * 8]);
        acc[t] = __builtin_amdgcn_mfma_f32_16x16x32_bf16(af, bfr, acc[t], 0, 0, 0);
      }
    }

    // ---- elementwise: c = w * theta * rsqrt(||v||^2) ----
    float sd[4] = {0.f, 0.f, 0.f, 0.f};
#pragma unroll
    for (int t = 0; t < 4; ++t) {
#pragma unroll
      for (int r = 0; r < 4; ++r) {
        float raw = acc[t][r];
        float dot = fminf(fmaxf(raw, -1.0f + EPSF), 1.0f - EPSF);
        float theta = fast_acos(dot);
        float nv2 = fmaf(dot * dot, pp[r], fmaf(-2.0f * dot, raw, 1.0f));
        float factor = (nv2 < 1e-14f) ? 1.0f : theta * rsqrtf(nv2);
        bf16 cb = (bf16)(wf[t][r] * factor);
        Ct[(obase + r) * TS2 + 16 * t + ln15] = cb;
        sd[r] = fmaf((float)cb, dot, sd[r]);
      }
    }
#pragma unroll
    for (int r = 0; r < 4; ++r) sd[r] = dpp_sum16(sd[r]);

    // ---- GEMM2: G[o][dd] ----
    f32x4 g[4] = {f32x4{0,0,0,0}, f32x4{0,0,0,0}, f32x4{0,0,0,0}, f32x4{0,0,0,0}};
#pragma unroll
    for (int ks = 0; ks < 2; ++ks) {
      bf16x8 af = *reinterpret_cast<const bf16x8*>(&ctbase[ks * 32 + quad * 8]);
#pragma unroll
      for (int t = 0; t < 4; ++t) {
        bf16x8 bfr = *reinterpret_cast<const bf16x8*>(
            &Xt[(16 * t + ln15) * TS2 + ks * 32 + quad * 8]);
        g[t] = __builtin_amdgcn_mfma_f32_16x16x32_bf16(af, bfr, g[t], 0, 0, 0);
      }
    }

    // ---- grad = G - sdot*a ; exp map ----
    float gn2[4] = {0.f, 0.f, 0.f, 0.f};
#pragma unroll
    for (int t = 0; t < 4; ++t)
#pragma unroll
      for (int r = 0; r < 4; ++r) {
        float v = g[t][r] - sd[r] * a_reg[t][r];
        g[t][r] = v;
        gn2[r] = fmaf(v, v, gn2[r]);
      }
#pragma unroll
    for (int r = 0; r < 4; ++r) {
      float nrm = sqrtf(dpp_sum16(gn2[r]));
      float sn_, cn;
      __sincosf(nrm, &sn_, &cn);
      float sn = (nrm < EPSF) ? 1.0f : sn_ / nrm;
#pragma unroll
      for (int t = 0; t < 4; ++t)
        a_reg[t][r] = fmaf(cn, a_reg[t][r], sn * g[t][r]);
    }
    if (it < 2) {
#pragma unroll
      for (int t = 0; t < 4; ++t)
#pragma unroll
        for (int r = 0; r < 4; ++r)
          Arow[(obase + r) * TS2 + 16 * t + ln15] = (bf16)a_reg[t][r];
    }
  }

  // ---- epilogue: LDS fp32 transpose -> coalesced float4 stores ----
  __syncthreads();  // done reading Xrow/Xt before aliasing
#pragma unroll
  for (int t = 0; t < 4; ++t)
#pragma unroll
    for (int r = 0; r < 4; ++r)
      OutF[(obase + r) * OFS + 16 * t + ln15] = a_reg[t][r];
  __syncthreads();
  float* outn = out + (size_t)n * 4096;
#pragma unroll
  for (int t = 0; t < 4; ++t) {
    int idx = tid + t * 256;
    int row = idx >> 4, col4 = (idx & 15) << 2;
    float4 v = *reinterpret_cast<const float4*>(&OutF[row * OFS + col4]);
    reinterpret_cast<float4*>(outn)[idx] = v;
  }
}

extern "C" void kernel_launch(void* const* d_in, const int* in_sizes, int n_in,
                              void* d_out, int out_size, void* d_ws, size_t ws_size,
                              hipStream_t stream) {
  const float* x = (const float*)d_in[0];    // (B,L,64,64) fp32, unit rows
  const float* wraw = (const float*)d_in[1]; // (64,64) fp32
  float* out = (float*)d_out;                // (B,L,64,64) fp32
  (void)d_ws; (void)ws_size;

  int N = in_sizes[0] / 4096;  // B*L = 1024

  mfd_fc_mfma<<<N, 256, 0, stream>>>(x, wraw, out);
}

// Round 5
// 91.249 us; speedup vs baseline: 1.5876x; 1.0687x over previous
//
#include <hip/hip_runtime.h>

#define EPSF 1e-7f
#define TS2 72   // bf16 row stride: 64 + 8 pad (16B-aligned rows, bank-rotating)
#define OFS 68   // fp32 out-staging row stride

typedef __bf16 bf16;
typedef __attribute__((ext_vector_type(8))) __bf16 bf16x8;
typedef __attribute__((ext_vector_type(4))) __bf16 bf16x4;
typedef __attribute__((ext_vector_type(4))) float f32x4;

// Sum over each 16-lane group via DPP involutions: xor1, xor2 (quad_perm),
// xor7 (ROW_HALF_MIRROR), xor15 (ROW_MIRROR). Zero LDS traffic.
__device__ __forceinline__ float dpp_sum16(float v) {
  int x;
  x = __builtin_amdgcn_update_dpp(0, __builtin_bit_cast(int, v), 0xB1, 0xf, 0xf, true);
  v += __builtin_bit_cast(float, x);                     // + lane^1
  x = __builtin_amdgcn_update_dpp(0, __builtin_bit_cast(int, v), 0x4E, 0xf, 0xf, true);
  v += __builtin_bit_cast(float, x);                     // + lane^2
  x = __builtin_amdgcn_update_dpp(0, __builtin_bit_cast(int, v), 0x141, 0xf, 0xf, true);
  v += __builtin_bit_cast(float, x);                     // + lane^7 (half mirror)
  x = __builtin_amdgcn_update_dpp(0, __builtin_bit_cast(int, v), 0x140, 0xf, 0xf, true);
  v += __builtin_bit_cast(float, x);                     // + lane^15 (mirror)
  return v;
}

// acos via A&S 4.4.45: |err| <= ~7e-5 rad.
__device__ __forceinline__ float fast_acos(float x) {
  float ax = fabsf(x);
  float r = sqrtf(fmaxf(1.0f - ax, 0.0f));
  float p = fmaf(fmaf(fmaf(-0.0187292994f, ax, 0.0742610070f), ax,
                      -0.2121144013f), ax, 1.5707288f);
  float t = r * p;
  return (x < 0.0f) ? (3.14159265358979f - t) : t;
}

// TWO samples per block (in-wave ILP: two independent dependency chains per
// wave). 4 waves; wave wv owns o-rows [16wv,16wv+16) of BOTH samples.
// GEMM1 (MFMA): dotT[o][i] = sum_dd a[o][dd]*x[i][dd]  (A=AC, B=Xrow)
// GEMM2 (MFMA): G[o][dd]   = sum_i  c[i][o]*x[i][dd]   (A=AC, B=Xt)
// AC holds Arow then Ct in the SAME storage: rows are wave-private and within
// an iter every Arow read precedes the first Ct write in program order (LDS
// ops of a wave are in-order), so aliasing is safe and halves that footprint.
// pp == 1: 'a' is an exp-map output (unit norm to fp error); error enters
// nv^2 as dot^2 * O(5e-4) -> <=1e-4 in output vs 1.19e-2 tolerance.
__global__ __launch_bounds__(256, 2) void mfd_fc_mfma2(
    const float* __restrict__ x, const float* __restrict__ wraw,
    float* __restrict__ out) {
  __shared__ __align__(16) char smem[6 * 64 * TS2 * sizeof(bf16)];  // 55296 B

  const int n0 = blockIdx.x * 2;
  const int tid = threadIdx.x;
  const int wv = tid >> 6;
  const int lane = tid & 63;
  const int ln15 = lane & 15;
  const int quad = lane >> 4;
  const int obase = 16 * wv + 4 * quad;

  bf16* Xrow[2]; bf16* Xt[2]; bf16* AC[2];
  float* OutF[2];
#pragma unroll
  for (int s = 0; s < 2; ++s) {
    bf16* b = (bf16*)smem + s * (3 * 64 * TS2);
    Xrow[s] = b;                 // [i][dd]
    Xt[s] = b + 64 * TS2;        // [dd][i]
    AC[s] = b + 2 * 64 * TS2;    // [o][dd] as Arow / [o][i] as Ct (aliased)
    OutF[s] = (float*)b;         // epilogue: aliases Xrow+Xt (17408 <= 18432)
  }
  const float* xbase = x + (size_t)n0 * 4096;

  // ---- stage both samples -> Xrow (bf16), coalesced float4 loads ----
#pragma unroll
  for (int t = 0; t < 8; ++t) {
    const int s = t >> 2;            // tid + t*256: t<4 -> sample 0, else 1
    int idx = tid + t * 256;         // float4 index over 2*1024
    int idx1 = idx & 1023;
    int i = idx1 >> 4;
    int c4 = (idx1 & 15) << 2;
    float4 v = reinterpret_cast<const float4*>(xbase)[idx];
    bf16x4 b;
    b[0] = (bf16)v.x; b[1] = (bf16)v.y; b[2] = (bf16)v.z; b[3] = (bf16)v.w;
    *reinterpret_cast<bf16x4*>(&Xrow[s][i * TS2 + c4]) = b;
  }

  // ---- per-wave softmax of wraw columns [obase..obase+3] (shared by both) --
  float wf[4][4];
  {
    float cs[4] = {0.f, 0.f, 0.f, 0.f};
#pragma unroll
    for (int t = 0; t < 4; ++t) {
      float4 wr = *reinterpret_cast<const float4*>(&wraw[(16 * t + ln15) * 64 + obase]);
      wf[t][0] = __expf(wr.x); wf[t][1] = __expf(wr.y);
      wf[t][2] = __expf(wr.z); wf[t][3] = __expf(wr.w);
#pragma unroll
      for (int r = 0; r < 4; ++r) cs[r] += wf[t][r];
    }
#pragma unroll
    for (int r = 0; r < 4; ++r) {
      float inv = 1.0f / dpp_sum16(cs[r]);
#pragma unroll
      for (int t = 0; t < 4; ++t) wf[t][r] *= inv;
    }
  }

  // ---- a := x0 per sample; write Arow (wave-private rows) ----
  float a_reg[2][4][4];
#pragma unroll
  for (int s = 0; s < 2; ++s)
#pragma unroll
    for (int t = 0; t < 4; ++t) {
      float v = xbase[s * 4096 + 16 * t + ln15];
#pragma unroll
      for (int r = 0; r < 4; ++r) a_reg[s][t][r] = v;
    }
#pragma unroll
  for (int s = 0; s < 2; ++s)
#pragma unroll
    for (int t = 0; t < 4; ++t)
#pragma unroll
      for (int r = 0; r < 4; ++r)
        AC[s][(obase + r) * TS2 + 16 * t + ln15] = (bf16)a_reg[s][t][r];

  __syncthreads();  // Xrow complete

  // ---- build Xt from Xrow (u16 column reads = pair-broadcast, no conflict) -
  {
    int dd = tid & 63, ih = tid >> 6;  // i-range [16*ih, 16*ih+16)
#pragma unroll
    for (int s = 0; s < 2; ++s) {
      bf16 tmp[16];
#pragma unroll
      for (int j = 0; j < 16; ++j) tmp[j] = Xrow[s][(16 * ih + j) * TS2 + dd];
      *reinterpret_cast<bf16x8*>(&Xt[s][dd * TS2 + 16 * ih]) =
          *reinterpret_cast<bf16x8*>(&tmp[0]);
      *reinterpret_cast<bf16x8*>(&Xt[s][dd * TS2 + 16 * ih + 8]) =
          *reinterpret_cast<bf16x8*>(&tmp[8]);
    }
  }
  __syncthreads();  // Xt complete; Xrow/Xt read-only until epilogue

  const bf16* acbase[2] = {&AC[0][(16 * wv + ln15) * TS2],
                           &AC[1][(16 * wv + ln15) * TS2]};

  for (int it = 0; it < 3; ++it) {
    // ---- GEMM1 both samples: dotT[o][i] ----
    f32x4 acc[2][4];
#pragma unroll
    for (int s = 0; s < 2; ++s)
#pragma unroll
      for (int t = 0; t < 4; ++t) acc[s][t] = f32x4{0, 0, 0, 0};
#pragma unroll
    for (int s = 0; s < 2; ++s)
#pragma unroll
      for (int ks = 0; ks < 2; ++ks) {
        bf16x8 af = *reinterpret_cast<const bf16x8*>(&acbase[s][ks * 32 + quad * 8]);
#pragma unroll
        for (int t = 0; t < 4; ++t) {
          bf16x8 bfr = *reinterpret_cast<const bf16x8*>(
              &Xrow[s][(16 * t + ln15) * TS2 + ks * 32 + quad * 8]);
          acc[s][t] = __builtin_amdgcn_mfma_f32_16x16x32_bf16(af, bfr, acc[s][t], 0, 0, 0);
        }
      }

    // ---- elementwise both samples: c = w * theta * rsqrt(1 - 2*dot*raw + dot^2)
    float sd[2][4] = {};
#pragma unroll
    for (int s = 0; s < 2; ++s)
#pragma unroll
      for (int t = 0; t < 4; ++t)
#pragma unroll
        for (int r = 0; r < 4; ++r) {
          float raw = acc[s][t][r];
          float dot = fminf(fmaxf(raw, -1.0f + EPSF), 1.0f - EPSF);
          float theta = fast_acos(dot);
          float nv2 = fmaf(dot, dot, fmaf(-2.0f * dot, raw, 1.0f));  // pp==1
          float factor = (nv2 < 1e-14f) ? 1.0f : theta * rsqrtf(nv2);
          bf16 cb = (bf16)(wf[t][r] * factor);
          AC[s][(obase + r) * TS2 + 16 * t + ln15] = cb;  // Arow -> Ct (safe alias)
          sd[s][r] = fmaf((float)cb, dot, sd[s][r]);
        }
#pragma unroll
    for (int s = 0; s < 2; ++s)
#pragma unroll
      for (int r = 0; r < 4; ++r) sd[s][r] = dpp_sum16(sd[s][r]);

    // ---- GEMM2 both samples: G[o][dd] ----
    f32x4 g[2][4];
#pragma unroll
    for (int s = 0; s < 2; ++s)
#pragma unroll
      for (int t = 0; t < 4; ++t) g[s][t] = f32x4{0, 0, 0, 0};
#pragma unroll
    for (int s = 0; s < 2; ++s)
#pragma unroll
      for (int ks = 0; ks < 2; ++ks) {
        bf16x8 af = *reinterpret_cast<const bf16x8*>(&acbase[s][ks * 32 + quad * 8]);
#pragma unroll
        for (int t = 0; t < 4; ++t) {
          bf16x8 bfr = *reinterpret_cast<const bf16x8*>(
              &Xt[s][(16 * t + ln15) * TS2 + ks * 32 + quad * 8]);
          g[s][t] = __builtin_amdgcn_mfma_f32_16x16x32_bf16(af, bfr, g[s][t], 0, 0, 0);
        }
      }

    // ---- grad = G - sdot*a ; exp map (registers only) ----
    float gn2[2][4] = {};
#pragma unroll
    for (int s = 0; s < 2; ++s)
#pragma unroll
      for (int t = 0; t < 4; ++t)
#pragma unroll
        for (int r = 0; r < 4; ++r) {
          float v = g[s][t][r] - sd[s][r] * a_reg[s][t][r];
          g[s][t][r] = v;
          gn2[s][r] = fmaf(v, v, gn2[s][r]);
        }
#pragma unroll
    for (int s = 0; s < 2; ++s)
#pragma unroll
      for (int r = 0; r < 4; ++r) {
        float nrm = sqrtf(dpp_sum16(gn2[s][r]));
        float sn_, cn;
        __sincosf(nrm, &sn_, &cn);
        float sn = (nrm < EPSF) ? 1.0f : sn_ / nrm;
#pragma unroll
        for (int t = 0; t < 4; ++t)
          a_reg[s][t][r] = fmaf(cn, a_reg[s][t][r], sn * g[s][t][r]);
      }
    if (it < 2) {
#pragma unroll
      for (int s = 0; s < 2; ++s)
#pragma unroll
        for (int t = 0; t < 4; ++t)
#pragma unroll
          for (int r = 0; r < 4; ++r)
            AC[s][(obase + r) * TS2 + 16 * t + ln15] = (bf16)a_reg[s][t][r];
    }
  }

  // ---- epilogue: LDS fp32 transpose -> coalesced float4 stores ----
  __syncthreads();  // all waves done with Xrow/Xt before aliasing as OutF
#pragma unroll
  for (int s = 0; s < 2; ++s)
#pragma unroll
    for (int t = 0; t < 4; ++t)
#pragma unroll
      for (int r = 0; r < 4; ++r)
        OutF[s][(obase + r) * OFS + 16 * t + ln15] = a_reg[s][t][r];
  __syncthreads();
  float* outbase = out + (size_t)n0 * 4096;
#pragma unroll
  for (int t = 0; t < 8; ++t) {
    const int s = t >> 2;
    int idx = tid + t * 256;
    int idx1 = idx & 1023;
    int row = idx1 >> 4, col4 = (idx1 & 15) << 2;
    float4 v = *reinterpret_cast<const float4*>(&OutF[s][row * OFS + col4]);
    reinterpret_cast<float4*>(outbase)[idx] = v;
  }
}

extern "C" void kernel_launch(void* const* d_in, const int* in_sizes, int n_in,
                              void* d_out, int out_size, void* d_ws, size_t ws_size,
                              hipStream_t stream) {
  const float* x = (const float*)d_in[0];    // (B,L,64,64) fp32, unit rows
  const float* wraw = (const float*)d_in[1]; // (64,64) fp32
  float* out = (float*)d_out;                // (B,L,64,64) fp32
  (void)d_ws; (void)ws_size;

  int N = in_sizes[0] / 4096;  // B*L = 1024
  mfd_fc_mfma2<<<N / 2, 256, 0, stream>>>(x, wraw, out);
}

// Round 6
// 84.043 us; speedup vs baseline: 1.7237x; 1.0857x over previous
//
#include <hip/hip_runtime.h>

#define EPSF 1e-7f
#define TS2 72   // bf16 row stride: 64 + 8 pad (16B-aligned rows, bank-rotating)
#define OFS 68   // fp32 out-staging row stride

typedef __bf16 bf16;
typedef __attribute__((ext_vector_type(8))) __bf16 bf16x8;
typedef __attribute__((ext_vector_type(4))) __bf16 bf16x4;
typedef __attribute__((ext_vector_type(4))) float f32x4;

// Sum over each 16-lane group via DPP involutions. Zero LDS traffic.
__device__ __forceinline__ float dpp_sum16(float v) {
  int x;
  x = __builtin_amdgcn_update_dpp(0, __builtin_bit_cast(int, v), 0xB1, 0xf, 0xf, true);
  v += __builtin_bit_cast(float, x);                     // + lane^1
  x = __builtin_amdgcn_update_dpp(0, __builtin_bit_cast(int, v), 0x4E, 0xf, 0xf, true);
  v += __builtin_bit_cast(float, x);                     // + lane^2
  x = __builtin_amdgcn_update_dpp(0, __builtin_bit_cast(int, v), 0x141, 0xf, 0xf, true);
  v += __builtin_bit_cast(float, x);                     // + lane^7 (half mirror)
  x = __builtin_amdgcn_update_dpp(0, __builtin_bit_cast(int, v), 0x140, 0xf, 0xf, true);
  v += __builtin_bit_cast(float, x);                     // + lane^15 (mirror)
  return v;
}

// factor(dot) = acos(dot)/sqrt(1-dot^2) = theta/sin(theta), fused via
// A&S 4.4.45: acos(x)=sqrt(1-x)*P(x) for x>=0. Then
//   dot>=0: P(dot)*rsqrt(1+dot)
//   dot< 0: (pi*rsqrt(1-|dot|) - P(|dot|)) * rsqrt(1+|dot|)
// Exact where it matters (pp==1, raw==dot away from clamp; clamped i=0/it=0
// case contributes O(1e-4*w) in both ref and here). 2 v_rsq + 5 FMA.
__device__ __forceinline__ float fused_factor(float dot) {
  float ax = fabsf(dot);
  float q2 = __builtin_amdgcn_rsqf(1.0f + ax);
  float r2 = __builtin_amdgcn_rsqf(1.0f - ax);   // dot clamped -> 1-ax >= EPSF
  float pa = fmaf(fmaf(fmaf(-0.0187292994f, ax, 0.0742610070f), ax,
                       -0.2121144013f), ax, 1.5707288f);
  float sel = (dot < 0.0f) ? fmaf(3.14159265358979f, r2, -pa) : pa;
  return sel * q2;
}

// One block = one sample n; 4 waves; wave wv owns o-rows [16wv,16wv+16).
// GEMM1 (MFMA): dotT[o][i] = sum_dd a[o][dd]*x[i][dd]  (A=AC(Arow), B=Xrow)
// GEMM2 (MFMA): G[o][dd]   = sum_i  c[i][o]*x[i][dd]   (A=AC(Ct),   B=Xt)
// AC holds Arow then Ct in the SAME storage: rows are wave-private and every
// Arow read precedes the first Ct write in program order (same-wave LDS ops
// are in-order), so aliasing is safe. LDS = 27648 B -> 4 blocks/CU resident
// (grid 1024 = 4 x 256 CUs exactly), 16 waves/CU.
__global__ __launch_bounds__(256, 4) void mfd_fc_mfma(
    const float* __restrict__ x, const float* __restrict__ wraw,
    float* __restrict__ out) {
  __shared__ __align__(16) char smem[3 * 64 * TS2 * sizeof(bf16)];  // 27648 B
  bf16* Xrow = (bf16*)smem;            // [i][dd]
  bf16* Xt   = Xrow + 64 * TS2;        // [dd][i]
  bf16* AC   = Xt + 64 * TS2;          // [o][dd] as Arow / [o][i] as Ct
  float* OutF = (float*)smem;          // epilogue: aliases Xrow+Xt (17408 B)

  const int n = blockIdx.x;
  const int tid = threadIdx.x;
  const int wv = tid >> 6;
  const int lane = tid & 63;
  const int ln15 = lane & 15;
  const int quad = lane >> 4;
  const int obase = 16 * wv + 4 * quad;
  const float* xn = x + (size_t)n * 4096;

  // ---- stage X -> Xrow (bf16), coalesced float4 loads ----
#pragma unroll
  for (int t = 0; t < 4; ++t) {
    int idx = tid + t * 256;  // float4 index
    int i = idx >> 4;
    int c4 = (idx & 15) << 2;
    float4 v = reinterpret_cast<const float4*>(xn)[idx];
    bf16x4 b;
    b[0] = (bf16)v.x; b[1] = (bf16)v.y; b[2] = (bf16)v.z; b[3] = (bf16)v.w;
    *reinterpret_cast<bf16x4*>(&Xrow[i * TS2 + c4]) = b;
  }

  // ---- per-wave softmax of wraw columns [obase..obase+3] ----
  float wf[4][4];
  {
    float cs[4] = {0.f, 0.f, 0.f, 0.f};
#pragma unroll
    for (int t = 0; t < 4; ++t) {
      float4 wr = *reinterpret_cast<const float4*>(&wraw[(16 * t + ln15) * 64 + obase]);
      wf[t][0] = __expf(wr.x); wf[t][1] = __expf(wr.y);
      wf[t][2] = __expf(wr.z); wf[t][3] = __expf(wr.w);
#pragma unroll
      for (int r = 0; r < 4; ++r) cs[r] += wf[t][r];
    }
#pragma unroll
    for (int r = 0; r < 4; ++r) {
      float inv = __builtin_amdgcn_rcpf(dpp_sum16(cs[r]));
#pragma unroll
      for (int t = 0; t < 4; ++t) wf[t][r] *= inv;
    }
  }

  // ---- a := x0 (fp32; dd = 16t+ln15, same value for all r) ----
  float a_reg[4][4];
#pragma unroll
  for (int t = 0; t < 4; ++t) {
    float v = xn[16 * t + ln15];
#pragma unroll
    for (int r = 0; r < 4; ++r) a_reg[t][r] = v;
  }
#pragma unroll
  for (int t = 0; t < 4; ++t)
#pragma unroll
    for (int r = 0; r < 4; ++r)
      AC[(obase + r) * TS2 + 16 * t + ln15] = (bf16)a_reg[t][r];

  __syncthreads();  // Xrow complete

  // ---- build Xt from Xrow (u16 column reads = pair-broadcast, no conflict) -
  {
    int dd = tid & 63, ih = tid >> 6;  // i-range [16*ih, 16*ih+16)
    bf16 tmp[16];
#pragma unroll
    for (int j = 0; j < 16; ++j) tmp[j] = Xrow[(16 * ih + j) * TS2 + dd];
    *reinterpret_cast<bf16x8*>(&Xt[dd * TS2 + 16 * ih]) =
        *reinterpret_cast<bf16x8*>(&tmp[0]);
    *reinterpret_cast<bf16x8*>(&Xt[dd * TS2 + 16 * ih + 8]) =
        *reinterpret_cast<bf16x8*>(&tmp[8]);
  }
  __syncthreads();  // Xt complete; Xrow/Xt read-only until epilogue

  const bf16* acbase = &AC[(16 * wv + ln15) * TS2];

  for (int it = 0; it < 3; ++it) {
    // ---- GEMM1: dotT[o][i] ----
    f32x4 acc[4] = {f32x4{0,0,0,0}, f32x4{0,0,0,0}, f32x4{0,0,0,0}, f32x4{0,0,0,0}};
#pragma unroll
    for (int ks = 0; ks < 2; ++ks) {
      bf16x8 af = *reinterpret_cast<const bf16x8*>(&acbase[ks * 32 + quad * 8]);
#pragma unroll
      for (int t = 0; t < 4; ++t) {
        bf16x8 bfr = *reinterpret_cast<const bf16x8*>(
            &Xrow[(16 * t + ln15) * TS2 + ks * 32 + quad * 8]);
        acc[t] = __builtin_amdgcn_mfma_f32_16x16x32_bf16(af, bfr, acc[t], 0, 0, 0);
      }
    }

    // ---- elementwise: c = w * fused_factor(dot); Arow rows become Ct ----
    float sd[4] = {0.f, 0.f, 0.f, 0.f};
#pragma unroll
    for (int t = 0; t < 4; ++t) {
#pragma unroll
      for (int r = 0; r < 4; ++r) {
        float raw = acc[t][r];
        float dot = fminf(fmaxf(raw, -1.0f + EPSF), 1.0f - EPSF);
        bf16 cb = (bf16)(wf[t][r] * fused_factor(dot));
        AC[(obase + r) * TS2 + 16 * t + ln15] = cb;  // safe alias (wave-private)
        sd[r] = fmaf((float)cb, dot, sd[r]);
      }
    }
#pragma unroll
    for (int r = 0; r < 4; ++r) sd[r] = dpp_sum16(sd[r]);

    // ---- GEMM2: G[o][dd] ----
    f32x4 g[4] = {f32x4{0,0,0,0}, f32x4{0,0,0,0}, f32x4{0,0,0,0}, f32x4{0,0,0,0}};
#pragma unroll
    for (int ks = 0; ks < 2; ++ks) {
      bf16x8 af = *reinterpret_cast<const bf16x8*>(&acbase[ks * 32 + quad * 8]);
#pragma unroll
      for (int t = 0; t < 4; ++t) {
        bf16x8 bfr = *reinterpret_cast<const bf16x8*>(
            &Xt[(16 * t + ln15) * TS2 + ks * 32 + quad * 8]);
        g[t] = __builtin_amdgcn_mfma_f32_16x16x32_bf16(af, bfr, g[t], 0, 0, 0);
      }
    }

    // ---- grad = G - sdot*a ; exp map with native v_sqrt/v_sin/v_cos/v_rcp --
    float gn2[4] = {0.f, 0.f, 0.f, 0.f};
#pragma unroll
    for (int t = 0; t < 4; ++t)
#pragma unroll
      for (int r = 0; r < 4; ++r) {
        float v = g[t][r] - sd[r] * a_reg[t][r];
        g[t][r] = v;
        gn2[r] = fmaf(v, v, gn2[r]);
      }
#pragma unroll
    for (int r = 0; r < 4; ++r) {
      float nrm = __builtin_amdgcn_sqrtf(dpp_sum16(gn2[r]));
      float rev = nrm * 0.15915494309189535f;     // v_sin/v_cos take revolutions
      float sn_ = __builtin_amdgcn_sinf(rev);
      float cn  = __builtin_amdgcn_cosf(rev);
      float sn = (nrm < EPSF) ? 1.0f : sn_ * __builtin_amdgcn_rcpf(nrm);
#pragma unroll
      for (int t = 0; t < 4; ++t)
        a_reg[t][r] = fmaf(cn, a_reg[t][r], sn * g[t][r]);
    }
    if (it < 2) {
#pragma unroll
      for (int t = 0; t < 4; ++t)
#pragma unroll
        for (int r = 0; r < 4; ++r)
          AC[(obase + r) * TS2 + 16 * t + ln15] = (bf16)a_reg[t][r];
    }
  }

  // ---- epilogue: LDS fp32 transpose -> coalesced float4 stores ----
  __syncthreads();  // all waves done with Xrow/Xt before aliasing as OutF
#pragma unroll
  for (int t = 0; t < 4; ++t)
#pragma unroll
    for (int r = 0; r < 4; ++r)
      OutF[(obase + r) * OFS + 16 * t + ln15] = a_reg[t][r];
  __syncthreads();
  float* outn = out + (size_t)n * 4096;
#pragma unroll
  for (int t = 0; t < 4; ++t) {
    int idx = tid + t * 256;
    int row = idx >> 4, col4 = (idx & 15) << 2;
    float4 v = *reinterpret_cast<const float4*>(&OutF[row * OFS + col4]);
    reinterpret_cast<float4*>(outn)[idx] = v;
  }
}

extern "C" void kernel_launch(void* const* d_in, const int* in_sizes, int n_in,
                              void* d_out, int out_size, void* d_ws, size_t ws_size,
                              hipStream_t stream) {
  const float* x = (const float*)d_in[0];    // (B,L,64,64) fp32, unit rows
  const float* wraw = (const float*)d_in[1]; // (64,64) fp32
  float* out = (float*)d_out;                // (B,L,64,64) fp32
  (void)d_ws; (void)ws_size;

  int N = in_sizes[0] / 4096;  // B*L = 1024
  mfd_fc_mfma<<<N, 256, 0, stream>>>(x, wraw, out);
}

// Round 7
// 83.190 us; speedup vs baseline: 1.7414x; 1.0103x over previous
//
#include <hip/hip_runtime.h>

#define EPSF 1e-7f
#define TS2 72   // bf16 row stride: 64 + 8 pad (16B-aligned rows, bank-rotating)
#define OFS 68   // fp32 out-staging row stride

typedef __bf16 bf16;
typedef __attribute__((ext_vector_type(8))) __bf16 bf16x8;
typedef __attribute__((ext_vector_type(4))) __bf16 bf16x4;
typedef __attribute__((ext_vector_type(4))) float f32x4;

// Sum over each 16-lane group via DPP involutions. Zero LDS traffic.
__device__ __forceinline__ float dpp_sum16(float v) {
  int x;
  x = __builtin_amdgcn_update_dpp(0, __builtin_bit_cast(int, v), 0xB1, 0xf, 0xf, true);
  v += __builtin_bit_cast(float, x);                     // + lane^1
  x = __builtin_amdgcn_update_dpp(0, __builtin_bit_cast(int, v), 0x4E, 0xf, 0xf, true);
  v += __builtin_bit_cast(float, x);                     // + lane^2
  x = __builtin_amdgcn_update_dpp(0, __builtin_bit_cast(int, v), 0x141, 0xf, 0xf, true);
  v += __builtin_bit_cast(float, x);                     // + lane^7 (half mirror)
  x = __builtin_amdgcn_update_dpp(0, __builtin_bit_cast(int, v), 0x140, 0xf, 0xf, true);
  v += __builtin_bit_cast(float, x);                     // + lane^15 (mirror)
  return v;
}

// factor(dot) = acos(dot)/sqrt(1-dot^2) = theta/sin(theta), fused via
// A&S 4.4.45: acos(x)=sqrt(1-x)*P(x) for x>=0. Then
//   dot>=0: P(dot)*rsqrt(1+dot)
//   dot< 0: (pi*rsqrt(1-|dot|) - P(|dot|)) * rsqrt(1+|dot|)
// pp==1 and raw==dot away from the clamp; clamped i=0/it=0 case contributes
// O(1e-4*w) in both ref and here. 2 v_rsq + ~7 VALU.
__device__ __forceinline__ float fused_factor(float dot) {
  float ax = fabsf(dot);
  float q2 = __builtin_amdgcn_rsqf(1.0f + ax);
  float r2 = __builtin_amdgcn_rsqf(1.0f - ax);   // dot clamped -> 1-ax >= EPSF
  float pa = fmaf(fmaf(fmaf(-0.0187292994f, ax, 0.0742610070f), ax,
                       -0.2121144013f), ax, 1.5707288f);
  float sel = (dot < 0.0f) ? fmaf(3.14159265358979f, r2, -pa) : pa;
  return sel * q2;
}

// One block = one sample n; 4 waves; wave wv owns o-rows [16wv,16wv+16).
// GEMM1 (MFMA): dotT[o][i] = sum_dd a[o][dd]*x[i][dd]  (A=AC(Arow), B=Xrow)
// GEMM2 (MFMA): G[o][dd]   = sum_i  c[i][o]*x[i][dd]   (A=AC(Ct),   B=Xt)
// GEMM1 B-fragments (Xrow) are iteration-invariant -> hoisted into 32 VGPRs
// right after the staging barrier; the K-loop's only LDS deps are the A-frag
// round-trips (wave-private AC rows, Arow/Ct aliased -> in-order safe) and
// the GEMM2 Xt reads (issued early, off the critical chain).
// Barrier schedule: [stage Xrow] sync [Xt build + Xrow->reg + GEMM1/elem it0]
// sync-once [GEMM2 it0; iters 1,2 barrier-free].
__global__ __launch_bounds__(256, 4) void mfd_fc_mfma(
    const float* __restrict__ x, const float* __restrict__ wraw,
    float* __restrict__ out) {
  __shared__ __align__(16) char smem[3 * 64 * TS2 * sizeof(bf16)];  // 27648 B
  bf16* Xrow = (bf16*)smem;            // [i][dd]
  bf16* Xt   = Xrow + 64 * TS2;        // [dd][i]
  bf16* AC   = Xt + 64 * TS2;          // [o][dd] as Arow / [o][i] as Ct
  float* OutF = (float*)smem;          // epilogue: aliases Xrow+Xt (17408 B)

  const int n = blockIdx.x;
  const int tid = threadIdx.x;
  const int wv = tid >> 6;
  const int lane = tid & 63;
  const int ln15 = lane & 15;
  const int quad = lane >> 4;
  const int obase = 16 * wv + 4 * quad;
  const float* xn = x + (size_t)n * 4096;

  // ---- stage X -> Xrow (bf16), coalesced float4 loads ----
#pragma unroll
  for (int t = 0; t < 4; ++t) {
    int idx = tid + t * 256;  // float4 index
    int i = idx >> 4;
    int c4 = (idx & 15) << 2;
    float4 v = reinterpret_cast<const float4*>(xn)[idx];
    bf16x4 b;
    b[0] = (bf16)v.x; b[1] = (bf16)v.y; b[2] = (bf16)v.z; b[3] = (bf16)v.w;
    *reinterpret_cast<bf16x4*>(&Xrow[i * TS2 + c4]) = b;
  }

  // ---- per-wave softmax of wraw columns [obase..obase+3] ----
  float wf[4][4];
  {
    float cs[4] = {0.f, 0.f, 0.f, 0.f};
#pragma unroll
    for (int t = 0; t < 4; ++t) {
      float4 wr = *reinterpret_cast<const float4*>(&wraw[(16 * t + ln15) * 64 + obase]);
      wf[t][0] = __expf(wr.x); wf[t][1] = __expf(wr.y);
      wf[t][2] = __expf(wr.z); wf[t][3] = __expf(wr.w);
#pragma unroll
      for (int r = 0; r < 4; ++r) cs[r] += wf[t][r];
    }
#pragma unroll
    for (int r = 0; r < 4; ++r) {
      float inv = __builtin_amdgcn_rcpf(dpp_sum16(cs[r]));
#pragma unroll
      for (int t = 0; t < 4; ++t) wf[t][r] *= inv;
    }
  }

  // ---- a := x0 (fp32; dd = 16t+ln15, same value for all r) ----
  float a_reg[4][4];
#pragma unroll
  for (int t = 0; t < 4; ++t) {
    float v = xn[16 * t + ln15];
#pragma unroll
    for (int r = 0; r < 4; ++r) a_reg[t][r] = v;
  }
#pragma unroll
  for (int t = 0; t < 4; ++t)
#pragma unroll
    for (int r = 0; r < 4; ++r)
      AC[(obase + r) * TS2 + 16 * t + ln15] = (bf16)a_reg[t][r];

  __syncthreads();  // Xrow complete

  // ---- build Xt from Xrow (u16 column reads = pair-broadcast) ----
  {
    int dd = tid & 63, ih = tid >> 6;  // i-range [16*ih, 16*ih+16)
    bf16 tmp[16];
#pragma unroll
    for (int j = 0; j < 16; ++j) tmp[j] = Xrow[(16 * ih + j) * TS2 + dd];
    *reinterpret_cast<bf16x8*>(&Xt[dd * TS2 + 16 * ih]) =
        *reinterpret_cast<bf16x8*>(&tmp[0]);
    *reinterpret_cast<bf16x8*>(&Xt[dd * TS2 + 16 * ih + 8]) =
        *reinterpret_cast<bf16x8*>(&tmp[8]);
  }
  // NOTE: no barrier yet — GEMM1/elementwise of it=0 only touch Xrow/AC.

  // ---- hoist GEMM1 B-fragments (Xrow is loop-invariant): 8 x bf16x8 ----
  bf16x8 xrf[4][2];
#pragma unroll
  for (int t = 0; t < 4; ++t)
#pragma unroll
    for (int ks = 0; ks < 2; ++ks)
      xrf[t][ks] = *reinterpret_cast<const bf16x8*>(
          &Xrow[(16 * t + ln15) * TS2 + ks * 32 + quad * 8]);

  const bf16* acbase = &AC[(16 * wv + ln15) * TS2];

  for (int it = 0; it < 3; ++it) {
    // ---- GEMM1: dotT[o][i] (B from registers) ----
    f32x4 acc[4] = {f32x4{0,0,0,0}, f32x4{0,0,0,0}, f32x4{0,0,0,0}, f32x4{0,0,0,0}};
#pragma unroll
    for (int ks = 0; ks < 2; ++ks) {
      bf16x8 af = *reinterpret_cast<const bf16x8*>(&acbase[ks * 32 + quad * 8]);
#pragma unroll
      for (int t = 0; t < 4; ++t)
        acc[t] = __builtin_amdgcn_mfma_f32_16x16x32_bf16(af, xrf[t][ks], acc[t], 0, 0, 0);
    }

    // ---- elementwise: c = w * fused_factor(dot); Arow rows become Ct ----
    float sd[4] = {0.f, 0.f, 0.f, 0.f};
#pragma unroll
    for (int t = 0; t < 4; ++t) {
#pragma unroll
      for (int r = 0; r < 4; ++r) {
        float raw = acc[t][r];
        float dot = __builtin_amdgcn_fmed3f(raw, -1.0f + EPSF, 1.0f - EPSF);
        bf16 cb = (bf16)(wf[t][r] * fused_factor(dot));
        AC[(obase + r) * TS2 + 16 * t + ln15] = cb;  // safe alias (wave-private)
        sd[r] = fmaf((float)cb, dot, sd[r]);
      }
    }
#pragma unroll
    for (int r = 0; r < 4; ++r) sd[r] = dpp_sum16(sd[r]);

    if (it == 0) __syncthreads();  // Xt complete (hidden behind GEMM1+elem)

    // ---- GEMM2: G[o][dd] ----
    f32x4 g[4] = {f32x4{0,0,0,0}, f32x4{0,0,0,0}, f32x4{0,0,0,0}, f32x4{0,0,0,0}};
#pragma unroll
    for (int ks = 0; ks < 2; ++ks) {
      bf16x8 af = *reinterpret_cast<const bf16x8*>(&acbase[ks * 32 + quad * 8]);
#pragma unroll
      for (int t = 0; t < 4; ++t) {
        bf16x8 bfr = *reinterpret_cast<const bf16x8*>(
            &Xt[(16 * t + ln15) * TS2 + ks * 32 + quad * 8]);
        g[t] = __builtin_amdgcn_mfma_f32_16x16x32_bf16(af, bfr, g[t], 0, 0, 0);
      }
    }

    // ---- grad = G - sdot*a ; exp map with native trans ops ----
    float gn2[4] = {0.f, 0.f, 0.f, 0.f};
#pragma unroll
    for (int t = 0; t < 4; ++t)
#pragma unroll
      for (int r = 0; r < 4; ++r) {
        float v = g[t][r] - sd[r] * a_reg[t][r];
        g[t][r] = v;
        gn2[r] = fmaf(v, v, gn2[r]);
      }
#pragma unroll
    for (int r = 0; r < 4; ++r) {
      float nrm = __builtin_amdgcn_sqrtf(dpp_sum16(gn2[r]));
      float rev = nrm * 0.15915494309189535f;     // v_sin/v_cos take revolutions
      float sn_ = __builtin_amdgcn_sinf(rev);
      float cn  = __builtin_amdgcn_cosf(rev);
      float sn = (nrm < EPSF) ? 1.0f : sn_ * __builtin_amdgcn_rcpf(nrm);
#pragma unroll
      for (int t = 0; t < 4; ++t)
        a_reg[t][r] = fmaf(cn, a_reg[t][r], sn * g[t][r]);
    }
    if (it < 2) {
#pragma unroll
      for (int t = 0; t < 4; ++t)
#pragma unroll
        for (int r = 0; r < 4; ++r)
          AC[(obase + r) * TS2 + 16 * t + ln15] = (bf16)a_reg[t][r];
    }
  }

  // ---- epilogue: LDS fp32 transpose -> coalesced float4 stores ----
  __syncthreads();  // all waves done with Xt before aliasing as OutF
#pragma unroll
  for (int t = 0; t < 4; ++t)
#pragma unroll
    for (int r = 0; r < 4; ++r)
      OutF[(obase + r) * OFS + 16 * t + ln15] = a_reg[t][r];
  __syncthreads();
  float* outn = out + (size_t)n * 4096;
#pragma unroll
  for (int t = 0; t < 4; ++t) {
    int idx = tid + t * 256;
    int row = idx >> 4, col4 = (idx & 15) << 2;
    float4 v = *reinterpret_cast<const float4*>(&OutF[row * OFS + col4]);
    reinterpret_cast<float4*>(outn)[idx] = v;
  }
}

extern "C" void kernel_launch(void* const* d_in, const int* in_sizes, int n_in,
                              void* d_out, int out_size, void* d_ws, size_t ws_size,
                              hipStream_t stream) {
  const float* x = (const float*)d_in[0];    // (B,L,64,64) fp32, unit rows
  const float* wraw = (const float*)d_in[1]; // (64,64) fp32
  float* out = (float*)d_out;                // (B,L,64,64) fp32
  (void)d_ws; (void)ws_size;

  int N = in_sizes[0] / 4096;  // B*L = 1024
  mfd_fc_mfma<<<N, 256, 0, stream>>>(x, wraw, out);
}